// Round 1
// 3108.094 us; speedup vs baseline: 1.0682x; 1.0682x over previous
//
#include <hip/hip_runtime.h>
#include <cstdint>
#include <cstddef>

// SNN pipeline, round 10:
//  k1: fp32 k-ascending FMA chains (BLAS replica, numerics IDENTICAL to round 9)
//      but rebalanced for the LDS pipe: 8x16 register tile (128 FMA per 6 b128
//      reads instead of 64 per 8 reads w/ 8-way conflicts), xs stride 132 so x
//      reads are aligned ds_read_b128 (4-addr broadcast, conflict-free), thread
//      column remap ht*16+j -> ht*4+64g+m so the four W b128 reads cover all 32
//      banks at the 2-access floor (conflict-free). Next-chunk global prefetch
//      issued before the 4096-FMA compute phase hides HBM latency. Same chains
//      per output element -> s1b bit-identical to round 9.
//  k2: unchanged math. Structural fix only: __syncthreads() forced a
//      vmcnt(0) drain of the just-issued gn prefetch every K-iter (the m97
//      barrier-drain stall). Replaced with s_waitcnt lgkmcnt(0) (ds_write
//      visibility) + raw s_barrier; the compiler's vmcnt wait now lands before
//      the NEXT iteration's ds_write of gv - one full MFMA phase after issue -
//      so prefetch stays in flight across the barrier (T3/T4 counted-wait).
//  k3: unchanged.
// ws: w2d 4MiB @0 | s1bits 128MiB @16MiB | po 80MiB @160MiB

typedef _Float16 f16;
typedef _Float16 f16x8 __attribute__((ext_vector_type(8)));
typedef float f32x4 __attribute__((ext_vector_type(4)));
typedef int i32x4 __attribute__((ext_vector_type(4)));

#define MFMA16(A, B, C) __builtin_amdgcn_mfma_f32_16x16x32_f16(A, B, C, 0, 0, 0)

static constexpr int BSZ = 65536;
static constexpr int IN = 512;
static constexpr int H = 1024;

// W2[k][j] fp32 -> w2d[plane][j][k] f16 Dekker limbs: plane0 = f16(w),
// plane1 = f16((w - hi) * 2^11).
__global__ void prep_dekker(const float* __restrict__ src, f16* __restrict__ dst) {
    int idx = blockIdx.x * 256 + threadIdx.x;
    int k = idx >> 10;
    int j = idx & 1023;
    float w = src[(size_t)k * 1024 + j];
    f16 hi = (f16)w;
    float lo = (w - (float)hi) * 2048.0f;
    size_t o = (size_t)j * 1024 + k;
    dst[o] = hi;
    dst[o + (size_t)H * H] = (f16)lo;
}

// k1: fp32 k-ordered FMA-chain GEMM (BLAS-replica) + fp32-replica LIF -> masks.
// tile 128 b-rows x 256 h-cols, 256 threads = 16 ht x 16 bt, thread = 8b x 16h.
// Thread's 16 cols are {h0 + 64g + ht*4 + m}: the 4 W-reads per k are b128 at
// 64-float stride -> 16 segments spread over all 32 banks (conflict-free).
__global__ __launch_bounds__(256, 2) void k1_chain(
    const float* __restrict__ x, const float* __restrict__ w1,
    const float* __restrict__ b1, unsigned short* __restrict__ s1b) {
    __shared__ float xs[32][132];   // [k][b]; stride 132: rows 16B-aligned, banks spread
    __shared__ float ws[32][256];   // [k][h]
    const int hblk = blockIdx.x;    // 4
    const int bblk = blockIdx.y;    // 512
    const int tid = threadIdx.x;
    const int ht = tid & 15, bt = tid >> 4;
    const int h0 = hblk * 256, b0 = bblk * 128;

    float acc[8][16] = {};

    float4 xv[4], wv[8];
    // preload chunk 0
#pragma unroll
    for (int i = 0; i < 4; ++i) {
        int idx = tid + 256 * i;            // 1024 f4: 128 rows x 8 segs
        int br = idx >> 3, ks = idx & 7;
        xv[i] = *(const float4*)&x[(size_t)(b0 + br) * IN + ks * 4];
    }
#pragma unroll
    for (int i = 0; i < 8; ++i) {
        int idx = tid + 256 * i;            // 2048 f4: 32 rows x 64 segs
        int kr = idx >> 6, c4 = idx & 63;
        wv[i] = *(const float4*)&w1[(size_t)kr * H + h0 + c4 * 4];
    }

    for (int kc = 0; kc < 512; kc += 32) {
        __syncthreads();                    // prev compute's LDS reads done
#pragma unroll
        for (int i = 0; i < 4; ++i) {
            int idx = tid + 256 * i;
            int br = idx >> 3, ks = idx & 7;
            xs[ks * 4 + 0][br] = xv[i].x;
            xs[ks * 4 + 1][br] = xv[i].y;
            xs[ks * 4 + 2][br] = xv[i].z;
            xs[ks * 4 + 3][br] = xv[i].w;
        }
#pragma unroll
        for (int i = 0; i < 8; ++i) {
            int idx = tid + 256 * i;
            int kr = idx >> 6, c4 = idx & 63;
            *(float4*)&ws[kr][c4 * 4] = wv[i];
        }
        __syncthreads();
        // prefetch next chunk (issues before compute; latency hides under FMAs)
        int kn = (kc + 32) & 511;           // wraps to 0 on last chunk (dummy)
#pragma unroll
        for (int i = 0; i < 4; ++i) {
            int idx = tid + 256 * i;
            int br = idx >> 3, ks = idx & 7;
            xv[i] = *(const float4*)&x[(size_t)(b0 + br) * IN + kn + ks * 4];
        }
#pragma unroll
        for (int i = 0; i < 8; ++i) {
            int idx = tid + 256 * i;
            int kr = idx >> 6, c4 = idx & 63;
            wv[i] = *(const float4*)&w1[(size_t)(kn + kr) * H + h0 + c4 * 4];
        }
#pragma unroll 2
        for (int k = 0; k < 32; ++k) {
            float xr[8];
            *(float4*)&xr[0] = *(const float4*)&xs[k][bt * 8];
            *(float4*)&xr[4] = *(const float4*)&xs[k][bt * 8 + 4];
            float wr[16];
#pragma unroll
            for (int g = 0; g < 4; ++g)
                *(float4*)&wr[g * 4] = *(const float4*)&ws[k][ht * 4 + 64 * g];
#pragma unroll
            for (int i = 0; i < 8; ++i)
#pragma unroll
                for (int j = 0; j < 16; ++j)
                    acc[i][j] = fmaf(xr[i], wr[j], acc[i][j]);  // strict k-order chain
        }
    }

    float b1v[16];
#pragma unroll
    for (int g = 0; g < 4; ++g)
#pragma unroll
        for (int m = 0; m < 4; ++m)
            b1v[g * 4 + m] = b1[h0 + g * 64 + ht * 4 + m];
#pragma unroll
    for (int i = 0; i < 8; ++i) {
        unsigned short outb[16];
#pragma unroll
        for (int j = 0; j < 16; ++j) {
            float c = __fadd_rn(acc[i][j], b1v[j]);
            float m = 0.0f;
            unsigned bits = 0u;
#pragma unroll
            for (int t = 0; t < 10; ++t) {
                float rst = (m > 1.0f) ? 1.0f : 0.0f;
                m = __fmul_rn(0.9f, m);
                m = __fadd_rn(m, c);
                m = __fsub_rn(m, rst);
                if (m > 1.0f) bits |= (1u << t);
            }
            outb[j] = (unsigned short)bits;
        }
        size_t row = (size_t)(b0 + bt * 8 + i);
#pragma unroll
        for (int g = 0; g < 4; ++g)
            *(int2*)&s1b[row * H + h0 + g * 64 + ht * 4] = ((const int2*)outb)[g];
    }
}

// k2: spike GEMM. Block = 64 rows x 32 cols, 512 threads = 8 waves:
// wave = (strip = w&3) x (thalf = w>>2). Fragment-linear LDS, BK=64.
// Raw s_barrier + explicit lgkmcnt(0): global prefetch stays in flight
// across the barrier (no per-iter vmcnt(0) drain).
__global__ __launch_bounds__(512, 4) void k2_spikes_gemm(
    const unsigned short* __restrict__ s1bits, const f16* __restrict__ w2d,
    const float* __restrict__ b2, const float* __restrict__ wo,
    float* __restrict__ po) {
    __shared__ i32x4 AL[2][2][4][64];       // [buf][kch][strip][lane-slot] 16 KB
    __shared__ i32x4 BL[2][2][2][2][64];    // [buf][kch][plane][cf][lane-slot] 16 KB
    __shared__ float m2x[4][64][8];         // m2 handoff t4 -> t5, 8 KB
    const int jblk = blockIdx.x, bblk = blockIdx.y;
    const int tid = threadIdx.x;
    const int lane = tid & 63, wave = tid >> 6;
    const int strip = wave & 3, thalf = wave >> 2;
    const int l15 = lane & 15, loct = lane >> 4;
    const int t0 = thalf * 5;

    // staging: threads 0-255 stage A, 256-511 stage B; slot = (seg<<4)|row
    // matches the MFMA fragment lane map -> stride-1 LDS writes AND reads.
    const bool stageB = (tid >= 256);
    const int s = tid & 255;
    const int sl15 = s & 15, sseg = (s >> 4) & 3;
    const int slot = (sseg << 4) | sl15;          // lane slot within its group
    const int astrip = s >> 6;                    // A: 4 strips
    const int bp = (s >> 7) & 1, bcf = (s >> 6) & 1;  // B: plane, colfrag

    const char* gsrc;
    if (stageB)
        gsrc = (const char*)(w2d + (size_t)bp * H * H
                             + (size_t)(jblk * 32 + bcf * 16 + sl15) * 1024 + sseg * 8);
    else
        gsrc = (const char*)(s1bits + (size_t)(bblk * 64 + astrip * 16 + sl15) * 1024 + sseg * 8);

    f32x4 acc[5][2][2] = {};   // [tt][plane][colfrag] = 80 regs

    i32x4 gv0 = *(const i32x4*)(gsrc);
    i32x4 gv1 = *(const i32x4*)(gsrc + 64);

    typedef union { i32x4 i; unsigned long long u[2]; f16x8 h; } U;

    int buf = 0;
    for (int kc = 0; kc < 1024; kc += 64) {
        // compiler inserts the vmcnt wait for gv here, one full MFMA phase
        // after those loads were issued -> essentially free.
        if (stageB) {
            BL[buf][0][bp][bcf][slot] = gv0;
            BL[buf][1][bp][bcf][slot] = gv1;
        } else {
            AL[buf][0][astrip][slot] = gv0;
            AL[buf][1][astrip][slot] = gv1;
        }
        int kn = (kc + 64) & 1023;   // wraps to 0 on last iter (dummy prefetch)
        i32x4 gn0 = *(const i32x4*)(gsrc + kn * 2);
        i32x4 gn1 = *(const i32x4*)(gsrc + kn * 2 + 64);
        // ds_write visibility for other waves, WITHOUT draining vmcnt:
        asm volatile("s_waitcnt lgkmcnt(0)" ::: "memory");
        __builtin_amdgcn_s_barrier();
#pragma unroll
        for (int kch = 0; kch < 2; ++kch) {
            U m;
            m.i = AL[buf][kch][strip][lane];
            f16x8 bf[2][2];
#pragma unroll
            for (int p = 0; p < 2; ++p)
#pragma unroll
                for (int cf = 0; cf < 2; ++cf) {
                    U b; b.i = BL[buf][kch][p][cf][lane];
                    bf[p][cf] = b.h;
                }
#pragma unroll
            for (int tt = 0; tt < 5; ++tt) {
                const int sh = 10 - (t0 + tt);
                U r;
                r.u[0] = (m.u[0] << sh) & 0x0400040004000400ULL;
                r.u[1] = (m.u[1] << sh) & 0x0400040004000400ULL;
                acc[tt][0][0] = MFMA16(r.h, bf[0][0], acc[tt][0][0]);
                acc[tt][0][1] = MFMA16(r.h, bf[0][1], acc[tt][0][1]);
                acc[tt][1][0] = MFMA16(r.h, bf[1][0], acc[tt][1][0]);
                acc[tt][1][1] = MFMA16(r.h, bf[1][1], acc[tt][1][1]);
            }
        }
        gv0 = gn0; gv1 = gn1;
        buf ^= 1;
    }

    // epilogue: Dekker combine (unpack scale folded in: 16384, 8),
    // fp32-replica LIF-2 split across t-halves with LDS m2 handoff.
    int col0 = jblk * 32 + l15;
    float b2v0 = b2[col0], b2v1 = b2[col0 + 16];
    double wov0 = (double)wo[col0], wov1 = (double)wo[col0 + 16];
    int rowb = bblk * 64 + strip * 16 + loct * 4;
    float m2a[4] = {0.0f, 0.0f, 0.0f, 0.0f};
    float m2b[4] = {0.0f, 0.0f, 0.0f, 0.0f};

    if (thalf == 0) {
#pragma unroll
        for (int tt = 0; tt < 5; ++tt) {
#pragma unroll
            for (int r = 0; r < 4; ++r) {
                float i0 = (float)((double)acc[tt][0][0][r] * 16384.0 + (double)acc[tt][1][0][r] * 8.0);
                i0 = __fadd_rn(i0, b2v0);
                float rst0 = (m2a[r] > 1.0f) ? 1.0f : 0.0f;
                m2a[r] = __fmul_rn(0.9f, m2a[r]);
                m2a[r] = __fadd_rn(m2a[r], i0);
                m2a[r] = __fsub_rn(m2a[r], rst0);
                float i1 = (float)((double)acc[tt][0][1][r] * 16384.0 + (double)acc[tt][1][1][r] * 8.0);
                i1 = __fadd_rn(i1, b2v1);
                float rst1 = (m2b[r] > 1.0f) ? 1.0f : 0.0f;
                m2b[r] = __fmul_rn(0.9f, m2b[r]);
                m2b[r] = __fadd_rn(m2b[r], i1);
                m2b[r] = __fsub_rn(m2b[r], rst1);
                double pv = ((m2a[r] > 1.0f) ? wov0 : 0.0) + ((m2b[r] > 1.0f) ? wov1 : 0.0);
                pv += __shfl_xor(pv, 1);
                pv += __shfl_xor(pv, 2);
                pv += __shfl_xor(pv, 4);
                pv += __shfl_xor(pv, 8);
                if (l15 == r)
                    po[(size_t)(tt * 32 + jblk) * BSZ + rowb + r] = (float)pv;
            }
        }
#pragma unroll
        for (int r = 0; r < 4; ++r) {
            m2x[strip][lane][r] = m2a[r];
            m2x[strip][lane][4 + r] = m2b[r];
        }
    }
    __syncthreads();
    if (thalf == 1) {
#pragma unroll
        for (int r = 0; r < 4; ++r) {
            m2a[r] = m2x[strip][lane][r];
            m2b[r] = m2x[strip][lane][4 + r];
        }
#pragma unroll
        for (int tt = 0; tt < 5; ++tt) {
#pragma unroll
            for (int r = 0; r < 4; ++r) {
                float i0 = (float)((double)acc[tt][0][0][r] * 16384.0 + (double)acc[tt][1][0][r] * 8.0);
                i0 = __fadd_rn(i0, b2v0);
                float rst0 = (m2a[r] > 1.0f) ? 1.0f : 0.0f;
                m2a[r] = __fmul_rn(0.9f, m2a[r]);
                m2a[r] = __fadd_rn(m2a[r], i0);
                m2a[r] = __fsub_rn(m2a[r], rst0);
                float i1 = (float)((double)acc[tt][0][1][r] * 16384.0 + (double)acc[tt][1][1][r] * 8.0);
                i1 = __fadd_rn(i1, b2v1);
                float rst1 = (m2b[r] > 1.0f) ? 1.0f : 0.0f;
                m2b[r] = __fmul_rn(0.9f, m2b[r]);
                m2b[r] = __fadd_rn(m2b[r], i1);
                m2b[r] = __fsub_rn(m2b[r], rst1);
                double pv = ((m2a[r] > 1.0f) ? wov0 : 0.0) + ((m2b[r] > 1.0f) ? wov1 : 0.0);
                pv += __shfl_xor(pv, 1);
                pv += __shfl_xor(pv, 2);
                pv += __shfl_xor(pv, 4);
                pv += __shfl_xor(pv, 8);
                if (l15 == r)
                    po[(size_t)((5 + tt) * 32 + jblk) * BSZ + rowb + r] = (float)pv;
            }
        }
    }
}

// k3: sum 32 partials (ascending j-blocks), fp32-replica LIF-out, mean.
__global__ void k3_out(const float* __restrict__ po, const float* __restrict__ bo,
                       float* __restrict__ out) {
    int b = blockIdx.x * 256 + threadIdx.x;
    float mo = 0.0f, s = 0.0f;
    float bov = bo[0];
    for (int t = 0; t < 10; ++t) {
        float inp = 0.0f;
#pragma unroll
        for (int jb = 0; jb < 32; ++jb) inp += po[(size_t)(t * 32 + jb) * BSZ + b];
        inp = __fadd_rn(inp, bov);
        float rst = (mo > 1.0f) ? 1.0f : 0.0f;
        mo = __fmul_rn(0.9f, mo);
        mo = __fadd_rn(mo, inp);
        mo = __fsub_rn(mo, rst);
        s += mo;
    }
    out[b] = s / 10.0f;
}

extern "C" void kernel_launch(void* const* d_in, const int* in_sizes, int n_in,
                              void* d_out, int out_size, void* d_ws, size_t ws_size,
                              hipStream_t stream) {
    (void)in_sizes; (void)n_in; (void)out_size; (void)ws_size;
    const float* x  = (const float*)d_in[0];
    const float* W1 = (const float*)d_in[1];
    const float* b1 = (const float*)d_in[2];
    const float* W2 = (const float*)d_in[3];
    const float* b2 = (const float*)d_in[4];
    const float* Wo = (const float*)d_in[5];
    const float* bo = (const float*)d_in[6];
    float* out = (float*)d_out;

    char* ws = (char*)d_ws;
    f16* w2d = (f16*)ws;                                                   // 4 MiB @ 0
    unsigned short* s1bits = (unsigned short*)(ws + ((size_t)16 << 20));   // 128 MiB
    float* po = (float*)(ws + ((size_t)160 << 20));                        // 80 MiB

    prep_dekker<<<dim3((H * H) / 256), 256, 0, stream>>>(W2, w2d);
    k1_chain<<<dim3(4, BSZ / 128), 256, 0, stream>>>(x, W1, b1, s1bits);
    k2_spikes_gemm<<<dim3(H / 32, BSZ / 64), 512, 0, stream>>>(s1bits, w2d, b2, Wo, po);
    k3_out<<<dim3(BSZ / 256), 256, 0, stream>>>(po, bo, out);
}